// Round 10
// baseline (4484.275 us; speedup 1.0000x reference)
//
#include <hip/hip_runtime.h>
#include <hip/hip_bf16.h>
#include <hip/hip_cooperative_groups.h>

namespace cg = cooperative_groups;

namespace {

typedef unsigned short u16;
constexpr int B_ = 256, V_ = 16, T_ = 64, P_ = 24, F_ = 8, H_ = 256, G_ = 1024;

typedef __attribute__((ext_vector_type(8))) short bf16x8;
typedef __attribute__((ext_vector_type(4))) float f32x4;

__device__ __forceinline__ float sigm(float x) { return 1.0f / (1.0f + __expf(-x)); }
__device__ __forceinline__ float bf2f(u16 s) {
  union { unsigned u; float f; } x; x.u = ((unsigned)s) << 16; return x.f;
}
__device__ __forceinline__ u16 f2bf(float f) {
  union { float f; unsigned u; } x; x.f = f;
  unsigned r = x.u + 0x7fffu + ((x.u >> 16) & 1u);
  return (u16)(r >> 16);
}
// split fp32 -> bf16 hi/lo pair (hi+lo carries ~16 mantissa bits)
__device__ __forceinline__ void split2(float w, u16& hi, u16& lo) {
  hi = f2bf(w);
  lo = f2bf(w - bf2f(hi));
}
__device__ __forceinline__ void load16(const void* g, void* l) {
  __builtin_amdgcn_global_load_lds(
      (const __attribute__((address_space(1))) unsigned*)g,
      (__attribute__((address_space(3))) unsigned*)l, 16, 0, 0);
}
__device__ __forceinline__ f32x4 mfma16(bf16x8 a, bf16x8 b, f32x4 c) {
  return __builtin_amdgcn_mfma_f32_16x16x32_bf16(a, b, c, 0, 0, 0);
}

// ---------------- init: zero c, prev = sequence[:,:,T-1,:] ----------------
__global__ void init_kernel(float* __restrict__ c, float* __restrict__ prev,
                            const float* __restrict__ seq) {
  int idx = blockIdx.x * 256 + threadIdx.x;
  if (idx < B_ * V_ * H_ / 4) ((float4*)c)[idx] = float4{0.f, 0.f, 0.f, 0.f};
  if (idx < B_ * V_ * F_ / 4) {
    int v = idx >> 9, rem = idx & 511;
    int b = rem >> 1, fq = rem & 1;
    ((float4*)prev)[idx] = ((const float4*)seq)[(((size_t)b * V_ + v) * T_ + (T_ - 1)) * 2 + fq];
  }
}

// ---------------- convert W_hh, W_att fp32 -> bf16 hi/lo pairs ----------------
__global__ void convert_kernel(const float* __restrict__ Whh, const float* __restrict__ Watt,
                               u16* __restrict__ whhH, u16* __restrict__ whhL,
                               u16* __restrict__ wattH, u16* __restrict__ wattL) {
  int gid = blockIdx.x * 256 + threadIdx.x;
  const int n1 = V_ * G_ * H_ / 4;       // 1048576 float4s
  const int n2 = V_ * H_ * 2 * H_ / 4;   // 524288
  const float* src; u16 *dH, *dL; int i;
  if (gid < n1)            { src = Whh;  dH = whhH;  dL = whhL;  i = gid; }
  else if (gid < n1 + n2)  { src = Watt; dH = wattH; dL = wattL; i = gid - n1; }
  else return;
  float4 wv = ((const float4*)src)[i];
  u16 h0,l0,h1,l1,h2,l2,h3,l3;
  split2(wv.x,h0,l0); split2(wv.y,h1,l1); split2(wv.z,h2,l2); split2(wv.w,h3,l3);
  uint2 oh; oh.x = (unsigned)h0 | ((unsigned)h1 << 16); oh.y = (unsigned)h2 | ((unsigned)h3 << 16);
  uint2 ol; ol.x = (unsigned)l0 | ((unsigned)l1 << 16); ol.y = (unsigned)l2 | ((unsigned)l3 << 16);
  ((uint2*)dH)[i] = oh; ((uint2*)dL)[i] = ol;
}

// ---------------- copy final encoder h -> hdec ----------------
__global__ void copy_h_kernel(const u16* __restrict__ enc, const u16* __restrict__ hlo1,
                              u16* __restrict__ hdecHi, u16* __restrict__ hdecLo) {
  int gid = blockIdx.x * 256 + threadIdx.x;   // 131072 uint4s
  int row = gid >> 5, jq = gid & 31;
  ((uint4*)hdecHi)[gid] = ((const uint4*)enc)[((size_t)row * T_ + (T_ - 1)) * 32 + jq];
  ((uint4*)hdecLo)[gid] = ((const uint4*)hlo1)[gid];
}

// ============ PERSISTENT ENCODER (cooperative, 1 launch, 64 steps) ============
// grid 256 = XCD-pinned (v = (bid&7)*2 + (bid>>3 &1)): all 16 blocks of a vessel
// live on one XCD, so h(t) write -> A(t+1) read stays in that XCD's L2.
// block 512 thr = 8 waves; tile 128 b x 128 gc; K=256.
// Whh hi/lo staged into LDS ONCE (128 KB, swizzled); A single-buffered (16 KB);
// xs in LDS (4 KB); W_ih/bias AND the c-state in registers across all steps.
// grid.sync() between steps (device fences make h(t-1) visible).
__global__ __launch_bounds__(512) void enc_persist_kernel(
    const float* __restrict__ seq,
    u16* __restrict__ enc,
    u16* __restrict__ h_lo,           // 2 buffers of V*B*H
    float* __restrict__ cbuf,         // final c (for decoder)
    const u16* __restrict__ WhhHi, const u16* __restrict__ WhhLo,
    const float* __restrict__ W_ih, const float* __restrict__ b_ih,
    const float* __restrict__ b_hh)
{
  __shared__ char smem[151552];
  // offsets: Bh 0, Bl 65536, Ah 131072, Al 139264, xs 147456 (4 KB) -> 151552 total
  float* xsf = (float*)(smem + 147456);

  cg::grid_group grid = cg::this_grid();

  int bid = blockIdx.x;
  int v  = (bid & 7) * 2 + ((bid >> 3) & 1);
  int bt = (bid >> 4) & 1;
  int ch = bid >> 5;                   // 0..7
  int b0 = bt * 128, c0 = ch * 32;
  int tid = threadIdx.x, lane = tid & 63, w = tid >> 6;
  int wr = w >> 1, wc = w & 1;
  int rA = lane & 15, kg = lane >> 4;
  int rowg = (lane >> 4) * 4;
  int cc = wc * 16 + rA;
  int col = c0 + cc;

  // ---- one-time: stage Whh hi/lo block-slice into LDS (swizzled source, linear dest) ----
  #pragma unroll
  for (int it = 0; it < 8; ++it) {
    int gidx = it * 512 + tid;           // 4096 granules of 16B each (64 KB)
    int row = gidx >> 5, gsub = gidx & 31;   // 32 granules per 512-B row
    int chunk = gsub >> 2, g2 = gsub & 3;
    int grow = ((row >> 5) << 8) + c0 + (row & 31);
    size_t off = ((((size_t)v * G_ + grow) * H_ + chunk * 32) << 1)
               + ((g2 ^ ((row >> 1) & 3)) << 4);
    load16((const char*)WhhHi + off, smem + gidx * 16);
    load16((const char*)WhhLo + off, smem + 65536 + gidx * 16);
  }

  // ---- one-time: W_ih rows + fused bias in registers ----
  float wih[4][8], bs[4];
  #pragma unroll
  for (int g = 0; g < 4; ++g) {
    int grow = (g << 8) + col;
    #pragma unroll
    for (int f = 0; f < 8; ++f) wih[g][f] = W_ih[((size_t)v * G_ + grow) * F_ + f];
    bs[g] = b_ih[v * G_ + grow] + b_hh[v * G_ + grow];
  }

  // ---- c-state in registers across all 64 steps ----
  float creg[2][4];
  #pragma unroll
  for (int i = 0; i < 2; ++i)
    #pragma unroll
    for (int r = 0; r < 4; ++r) creg[i][r] = 0.f;

  // read offsets
  int ar0 = wr * 32 + rA;
  int aoff0 = ar0 * 64 + ((kg ^ ((ar0 >> 1) & 3)) << 4);   // A row stride 64 B
  int brow[4], bxor[4];
  #pragma unroll
  for (int g = 0; g < 4; ++g) {
    int rowb = cc + g * 32;                                // B row stride 512 B
    brow[g] = rowb * 512;
    bxor[g] = ((kg ^ ((rowb >> 1) & 3)) << 4);
  }

  const size_t SZ = (size_t)V_ * B_ * H_;

  for (int t = 0; t < T_; ++t) {
    // stage x(t): 128 b x 8 f
    if (tid < 256) {
      int b_l = tid >> 1, fq = tid & 1;
      int b = b0 + b_l;
      float4 xv = *(const float4*)(seq + (((size_t)b * V_ + v) * T_ + t) * F_ + fq * 4);
      *(float4*)(xsf + b_l * 8 + fq * 4) = xv;
    }

    f32x4 acc[2][4];
    #pragma unroll
    for (int i = 0; i < 2; ++i)
      #pragma unroll
      for (int g = 0; g < 4; ++g) acc[i][g] = f32x4{0.f, 0.f, 0.f, 0.f};

    if (t > 0) {
      const u16* hloPrev = h_lo + ((t + 1) & 1) * SZ;      // (t-1)&1
      for (int ks = 0; ks < 8; ++ks) {
        {  // stage A[ks]: Ah from enc[t-1], Al from hloPrev (1 load16 each per thread)
          int row = tid >> 2, g2 = tid & 3;
          int kb = ((g2 ^ ((row >> 1) & 3)) << 4);
          size_t offH = ((((size_t)(v * B_ + b0 + row)) * T_ + (t - 1)) * H_ + ks * 32) * 2 + kb;
          size_t offL = (((size_t)(v * B_ + b0 + row)) * H_ + ks * 32) * 2 + kb;
          load16((const char*)enc + offH,     smem + 131072 + tid * 16);
          load16((const char*)hloPrev + offL, smem + 139264 + tid * 16);
        }
        __syncthreads();     // drains loads; also covers xs at ks==0
        const char* Ah = smem + 131072;
        const char* Al = smem + 139264;
        bf16x8 ah0 = *(const bf16x8*)(Ah + aoff0);
        bf16x8 ah1 = *(const bf16x8*)(Ah + aoff0 + 1024);
        bf16x8 al0 = *(const bf16x8*)(Al + aoff0);
        bf16x8 al1 = *(const bf16x8*)(Al + aoff0 + 1024);
        #pragma unroll
        for (int g = 0; g < 4; ++g) {
          bf16x8 bh = *(const bf16x8*)(smem + brow[g] + ks * 64 + bxor[g]);
          bf16x8 bl = *(const bf16x8*)(smem + 65536 + brow[g] + ks * 64 + bxor[g]);
          acc[0][g] = mfma16(ah0, bh, acc[0][g]);
          acc[1][g] = mfma16(ah1, bh, acc[1][g]);
          acc[0][g] = mfma16(al0, bh, acc[0][g]);
          acc[1][g] = mfma16(al1, bh, acc[1][g]);
          acc[0][g] = mfma16(ah0, bl, acc[0][g]);
          acc[1][g] = mfma16(ah1, bl, acc[1][g]);
        }
        __syncthreads();     // before next ks overwrites A
      }
    } else {
      __syncthreads();       // cover xs for t==0
    }

    // epilogue: + W_ih*x + bias; pointwise with c in registers
    u16* hloCur = h_lo + (t & 1) * SZ;
    #pragma unroll
    for (int i = 0; i < 2; ++i) {
      #pragma unroll
      for (int r = 0; r < 4; ++r) {
        int b_l = wr * 32 + i * 16 + rowg + r;
        const float* xf = xsf + b_l * 8;
        float s[4];
        #pragma unroll
        for (int g = 0; g < 4; ++g) {
          float sv = acc[i][g][r] + bs[g];
          #pragma unroll
          for (int f = 0; f < 8; ++f) sv = fmaf(wih[g][f], xf[f], sv);
          s[g] = sv;
        }
        float cn = sigm(s[1]) * creg[i][r] + sigm(s[0]) * tanhf(s[2]);
        float hn = sigm(s[3]) * tanhf(cn);
        creg[i][r] = cn;
        u16 hi, lo; split2(hn, hi, lo);
        enc[(((size_t)(v * B_ + b0 + b_l)) * T_ + t) * H_ + col] = hi;
        hloCur[((size_t)(v * B_ + b0 + b_l)) * H_ + col] = lo;
      }
    }
    grid.sync();             // h(t) visible to all blocks of this vessel
  }

  // final c -> global for the decoder
  #pragma unroll
  for (int i = 0; i < 2; ++i)
    #pragma unroll
    for (int r = 0; r < 4; ++r) {
      int b_l = wr * 32 + i * 16 + rowg + r;
      cbuf[((size_t)(v * B_ + b0 + b_l)) * H_ + col] = creg[i][r];
    }
}

// ---------------- decoder LSTM step (split-MFMA, per-launch) ----------------
// grid 256 = XCD-swizzled as in enc; block 512 thr; tile 128 b x 128 gc.
template <int MODE>
__global__ __launch_bounds__(512) void lstm_mfma_kernel(
    const float* __restrict__ xin,
    u16* __restrict__ enc,
    const u16* __restrict__ hloIn,
    u16* __restrict__ hloOut,
    const u16* __restrict__ aHi,
    const u16* __restrict__ aLo,
    u16* __restrict__ hdecHi, u16* __restrict__ hdecLo,
    float* __restrict__ cbuf,
    const u16* __restrict__ WhhHi, const u16* __restrict__ WhhLo,
    const float* __restrict__ W_ih, const float* __restrict__ b_ih,
    const float* __restrict__ b_hh,
    const float* __restrict__ maxv, const float* __restrict__ minv,
    int t)
{
  __shared__ char smem[74240];
  float* xsf   = (float*)(smem + 65536);
  float* wisf  = (float*)(smem + 69632);
  float* bsumf = (float*)(smem + 73728);

  int bid = blockIdx.x;
  int xcd = bid & 7, idx = bid >> 3;
  int v  = xcd * 2 + (idx & 1);
  int bt = (idx >> 1) & 1;
  int ch = idx >> 2;
  int b0 = bt * 128, c0 = ch * 32;
  int tid = threadIdx.x, lane = tid & 63, w = tid >> 6;
  int wr = w >> 1, wc = w & 1;

  if (tid < 256) {
    int b_l = tid >> 1, fq = tid & 1;
    int b = b0 + b_l;
    float4 xv;
    if (MODE == 0) {
      xv = *(const float4*)(xin + (((size_t)b * V_ + v) * T_ + t) * F_ + fq * 4);
    } else {
      float4 pv = *(const float4*)(xin + ((size_t)v * B_ + b) * F_ + fq * 4);
      float4 mx = *(const float4*)(maxv + b * F_ + fq * 4);
      float4 mn = *(const float4*)(minv + b * F_ + fq * 4);
      xv.x = pv.x * (mx.x - mn.x) + mn.x;
      xv.y = pv.y * (mx.y - mn.y) + mn.y;
      xv.z = pv.z * (mx.z - mn.z) + mn.z;
      xv.w = pv.w * (mx.w - mn.w) + mn.w;
    }
    *(float4*)(xsf + b_l * 8 + fq * 4) = xv;
  } else {
    int idx2 = tid - 256;
    int gc = idx2 >> 1, half = idx2 & 1;
    int grow = ((gc >> 5) << 8) + c0 + (gc & 31);
    *(float4*)(wisf + gc * 8 + half * 4) =
        *(const float4*)(W_ih + ((size_t)v * G_ + grow) * F_ + half * 4);
  }
  if (tid < 128) {
    int grow = ((tid >> 5) << 8) + c0 + (tid & 31);
    bsumf[tid] = b_ih[v * G_ + grow] + b_hh[v * G_ + grow];
  }

  const bool hasK = (MODE == 1) || (t > 0);

  auto stageAB = [&](int ks, int bufn) {
    int kc = ks * 32;
    int row = tid >> 2, g2 = tid & 3;
    int kb = ((g2 ^ ((row >> 1) & 3)) << 4);
    size_t boff = ((((size_t)v * G_ + ((row >> 5) << 8) + c0 + (row & 31)) * H_ + kc) << 1) + kb;
    load16((const char*)WhhHi + boff, smem + 32768 + bufn * 8192 + tid * 16);
    load16((const char*)WhhLo + boff, smem + 49152 + bufn * 8192 + tid * 16);
    if (MODE == 0) {
      size_t offH = ((((size_t)(v * B_ + b0 + row)) * T_ + (t - 1)) * H_ + kc) * 2 + kb;
      size_t offL = (((size_t)(v * B_ + b0 + row)) * H_ + kc) * 2 + kb;
      load16((const char*)enc + offH,   smem + bufn * 8192 + tid * 16);
      load16((const char*)hloIn + offL, smem + 16384 + bufn * 8192 + tid * 16);
    } else {
      size_t offA = (((size_t)(v * B_ + b0 + row)) * H_ + kc) * 2 + kb;
      load16((const char*)aHi + offA, smem + bufn * 8192 + tid * 16);
      load16((const char*)aLo + offA, smem + 16384 + bufn * 8192 + tid * 16);
    }
  };

  f32x4 acc[2][4];
  #pragma unroll
  for (int i = 0; i < 2; ++i)
    #pragma unroll
    for (int g = 0; g < 4; ++g) acc[i][g] = f32x4{0.f, 0.f, 0.f, 0.f};

  if (hasK) stageAB(0, 0);
  __syncthreads();

  if (hasK) {
    int rA = lane & 15, kg = lane >> 4;
    int ar0 = wr * 32 + rA;
    int aoff0 = ar0 * 64 + ((kg ^ ((ar0 >> 1) & 3)) << 4);
    int br0 = wc * 16 + rA;
    int boff0 = br0 * 64 + ((kg ^ ((br0 >> 1) & 3)) << 4);
    int buf = 0;
    for (int ks = 0; ks < 8; ++ks) {
      if (ks < 7) stageAB(ks + 1, buf ^ 1);
      const char* Ah = smem + buf * 8192;
      const char* Al = smem + 16384 + buf * 8192;
      const char* Bh = smem + 32768 + buf * 8192;
      const char* Bl = smem + 49152 + buf * 8192;
      bf16x8 ah0 = *(const bf16x8*)(Ah + aoff0);
      bf16x8 ah1 = *(const bf16x8*)(Ah + aoff0 + 1024);
      bf16x8 al0 = *(const bf16x8*)(Al + aoff0);
      bf16x8 al1 = *(const bf16x8*)(Al + aoff0 + 1024);
      bf16x8 bh[4], bl[4];
      #pragma unroll
      for (int g = 0; g < 4; ++g) {
        bh[g] = *(const bf16x8*)(Bh + boff0 + g * 2048);
        bl[g] = *(const bf16x8*)(Bl + boff0 + g * 2048);
      }
      #pragma unroll
      for (int g = 0; g < 4; ++g) {
        acc[0][g] = mfma16(ah0, bh[g], acc[0][g]);
        acc[1][g] = mfma16(ah1, bh[g], acc[1][g]);
      }
      #pragma unroll
      for (int g = 0; g < 4; ++g) {
        acc[0][g] = mfma16(al0, bh[g], acc[0][g]);
        acc[1][g] = mfma16(al1, bh[g], acc[1][g]);
      }
      #pragma unroll
      for (int g = 0; g < 4; ++g) {
        acc[0][g] = mfma16(ah0, bl[g], acc[0][g]);
        acc[1][g] = mfma16(ah1, bl[g], acc[1][g]);
      }
      __syncthreads();
      buf ^= 1;
    }
  }

  {
    int rA = lane & 15;
    int cc = wc * 16 + rA;
    int col = c0 + cc;
    float bs[4], wr8[4][8];
    #pragma unroll
    for (int g = 0; g < 4; ++g) {
      int gc = g * 32 + cc;
      bs[g] = bsumf[gc];
      #pragma unroll
      for (int f = 0; f < 8; ++f) wr8[g][f] = wisf[gc * 8 + f];
    }
    int rowg = (lane >> 4) * 4;
    #pragma unroll
    for (int i = 0; i < 2; ++i) {
      #pragma unroll
      for (int r = 0; r < 4; ++r) {
        int b_l = wr * 32 + i * 16 + rowg + r;
        const float* xf = xsf + b_l * 8;
        float s[4];
        #pragma unroll
        for (int g = 0; g < 4; ++g) {
          float sv = acc[i][g][r] + bs[g];
          #pragma unroll
          for (int f = 0; f < 8; ++f) sv = fmaf(wr8[g][f], xf[f], sv);
          s[g] = sv;
        }
        size_t gidx = ((size_t)(v * B_ + b0 + b_l)) * H_ + col;
        float cold = cbuf[gidx];
        float cn = sigm(s[1]) * cold + sigm(s[0]) * tanhf(s[2]);
        float hn = sigm(s[3]) * tanhf(cn);
        cbuf[gidx] = cn;
        u16 hi, lo; split2(hn, hi, lo);
        if (MODE == 0) {
          enc[(((size_t)(v * B_ + b0 + b_l)) * T_ + t) * H_ + col] = hi;
          hloOut[gidx] = lo;
        } else {
          hdecHi[gidx] = hi;
          hdecLo[gidx] = lo;
        }
      }
    }
  }
}

// ---------------- decoder attention: LDS-staged enc, score -> softmax -> cv ----------------
__global__ __launch_bounds__(256) void attn_kernel(
    const u16* __restrict__ enc, const u16* __restrict__ hHi, const u16* __restrict__ hLo,
    const float* __restrict__ mask, u16* __restrict__ cvHi, u16* __restrict__ cvLo)
{
  __shared__ u16 et[T_ * H_];     // 32 KB, linear
  __shared__ float hh[H_];
  __shared__ float ss[T_];
  int bx = blockIdx.x;
  int v = bx >> 8, b = bx & 255;
  int tid = threadIdx.x;

  const char* erow = (const char*)(enc + ((size_t)(v * B_ + b)) * T_ * H_);
  #pragma unroll
  for (int it2 = 0; it2 < 8; ++it2) {
    int gidx = it2 * 256 + tid;
    load16(erow + gidx * 16, (char*)et + gidx * 16);
  }
  {
    size_t hidx = ((size_t)v * B_ + b) * H_ + tid;
    hh[tid] = bf2f(hHi[hidx]) + bf2f(hLo[hidx]);
  }
  __syncthreads();

  int t = tid >> 2, part = tid & 3;
  const u16* ep = et + t * H_ + part * 64;
  float acc = 0.f;
  #pragma unroll
  for (int it = 0; it < 8; ++it) {
    uint4 uu = *(const uint4*)(ep + it * 8);
    const float* hp = &hh[part * 64 + it * 8];
    acc = fmaf(bf2f((u16)(uu.x & 0xffff)), hp[0], acc);
    acc = fmaf(bf2f((u16)(uu.x >> 16)),    hp[1], acc);
    acc = fmaf(bf2f((u16)(uu.y & 0xffff)), hp[2], acc);
    acc = fmaf(bf2f((u16)(uu.y >> 16)),    hp[3], acc);
    acc = fmaf(bf2f((u16)(uu.z & 0xffff)), hp[4], acc);
    acc = fmaf(bf2f((u16)(uu.z >> 16)),    hp[5], acc);
    acc = fmaf(bf2f((u16)(uu.w & 0xffff)), hp[6], acc);
    acc = fmaf(bf2f((u16)(uu.w >> 16)),    hp[7], acc);
  }
  acc += __shfl_xor(acc, 1, 64);
  acc += __shfl_xor(acc, 2, 64);
  if (part == 0) ss[t] = acc * mask[((size_t)b * V_ + v) * T_ + t];
  __syncthreads();

  if (tid < 64) {
    float s = ss[tid];
    float m = s;
    #pragma unroll
    for (int d = 32; d >= 1; d >>= 1) m = fmaxf(m, __shfl_xor(m, d, 64));
    float e = __expf(s - m);
    float se = e;
    #pragma unroll
    for (int d = 32; d >= 1; d >>= 1) se += __shfl_xor(se, d, 64);
    ss[tid] = e / se;
  }
  __syncthreads();

  int j = tid;
  float a = 0.f;
  #pragma unroll 8
  for (int tt = 0; tt < T_; ++tt)
    a = fmaf(ss[tt], bf2f(et[tt * H_ + j]), a);
  u16 hi, lo; split2(a, hi, lo);
  size_t cidx = ((size_t)v * B_ + b) * H_ + j;
  cvHi[cidx] = hi;
  cvLo[cidx] = lo;
}

// ---------------- h_att = tanh(W_att . cat + b_att), split-MFMA ----------------
__global__ __launch_bounds__(256) void attg_mfma_kernel(
    const u16* __restrict__ cvHi, const u16* __restrict__ cvLo,
    const u16* __restrict__ hdHi, const u16* __restrict__ hdLo,
    const u16* __restrict__ WattHi, const u16* __restrict__ WattLo,
    const float* __restrict__ b_att,
    u16* __restrict__ hattHi, u16* __restrict__ hattLo)
{
  __shared__ char smem[40960];
  int bx = blockIdx.x;
  int v = bx >> 4, bt = (bx >> 1) & 7, nh = bx & 1;
  int bp0 = bt * 32, n0 = nh * 128;
  int tid = threadIdx.x, lane = tid & 63, w = tid >> 6;

  auto stageAB = [&](int ks, int bufn) {
    int kc = ks * 32;
    #pragma unroll
    for (int it = 0; it < 2; ++it) {
      int gb = it * 256 + tid;
      int nl = gb >> 2, g2 = gb & 3;
      int kb = ((g2 ^ ((nl >> 1) & 3)) << 4);
      size_t off = ((((size_t)v * H_ + n0 + nl) * (2 * H_) + kc) << 1) + kb;
      load16((const char*)WattHi + off, smem + 8192  + bufn * 8192 + gb * 16);
      load16((const char*)WattLo + off, smem + 24576 + bufn * 8192 + gb * 16);
    }
    {
      int g = tid & 127;
      int b = g >> 2, g2 = g & 3;
      int kb = ((g2 ^ ((b >> 1) & 3)) << 4);
      int bp = bp0 + b;
      const u16* baseH = (bp < 128) ? (cvHi + ((size_t)v * B_ + 2 * bp) * H_)
                                    : (hdHi + ((size_t)v * B_ + 2 * (bp - 128)) * H_);
      const u16* baseL = (bp < 128) ? (cvLo + ((size_t)v * B_ + 2 * bp) * H_)
                                    : (hdLo + ((size_t)v * B_ + 2 * (bp - 128)) * H_);
      if (tid < 128) load16((const char*)baseH + kc * 2 + kb, smem + bufn * 2048 + g * 16);
      else           load16((const char*)baseL + kc * 2 + kb, smem + 4096 + bufn * 2048 + g * 16);
    }
  };

  f32x4 acc[2][2];
  #pragma unroll
  for (int i = 0; i < 2; ++i)
    #pragma unroll
    for (int j = 0; j < 2; ++j) acc[i][j] = f32x4{0.f, 0.f, 0.f, 0.f};

  stageAB(0, 0);
  __syncthreads();

  int rA = lane & 15, kg = lane >> 4;
  int aoff0 = rA * 64 + ((kg ^ ((rA >> 1) & 3)) << 4);
  int gc0 = w * 32 + rA;
  int boff0 = gc0 * 64 + ((kg ^ ((gc0 >> 1) & 3)) << 4);
  int buf = 0;
  for (int ks = 0; ks < 16; ++ks) {
    if (ks < 15) stageAB(ks + 1, buf ^ 1);
    const char* Ah = smem + buf * 2048;
    const char* Al = smem + 4096  + buf * 2048;
    const char* Bh = smem + 8192  + buf * 8192;
    const char* Bl = smem + 24576 + buf * 8192;
    bf16x8 ah0 = *(const bf16x8*)(Ah + aoff0);
    bf16x8 ah1 = *(const bf16x8*)(Ah + aoff0 + 1024);
    bf16x8 al0 = *(const bf16x8*)(Al + aoff0);
    bf16x8 al1 = *(const bf16x8*)(Al + aoff0 + 1024);
    bf16x8 bh0 = *(const bf16x8*)(Bh + boff0);
    bf16x8 bh1 = *(const bf16x8*)(Bh + boff0 + 1024);
    bf16x8 bl0 = *(const bf16x8*)(Bl + boff0);
    bf16x8 bl1 = *(const bf16x8*)(Bl + boff0 + 1024);
    acc[0][0] = mfma16(ah0, bh0, acc[0][0]);
    acc[0][1] = mfma16(ah0, bh1, acc[0][1]);
    acc[1][0] = mfma16(ah1, bh0, acc[1][0]);
    acc[1][1] = mfma16(ah1, bh1, acc[1][1]);
    acc[0][0] = mfma16(al0, bh0, acc[0][0]);
    acc[0][1] = mfma16(al0, bh1, acc[0][1]);
    acc[1][0] = mfma16(al1, bh0, acc[1][0]);
    acc[1][1] = mfma16(al1, bh1, acc[1][1]);
    acc[0][0] = mfma16(ah0, bl0, acc[0][0]);
    acc[0][1] = mfma16(ah0, bl1, acc[0][1]);
    acc[1][0] = mfma16(ah1, bl0, acc[1][0]);
    acc[1][1] = mfma16(ah1, bl1, acc[1][1]);
    __syncthreads();
    buf ^= 1;
  }

  int rowg = (lane >> 4) * 4;
  #pragma unroll
  for (int i = 0; i < 2; ++i)
    #pragma unroll
    for (int j = 0; j < 2; ++j) {
      int n = n0 + w * 32 + j * 16 + rA;
      float bias = b_att[v * H_ + n];
      #pragma unroll
      for (int r = 0; r < 4; ++r) {
        int bp = bp0 + i * 16 + rowg + r;
        float tv = tanhf(acc[i][j][r] + bias);
        u16 hi, lo; split2(tv, hi, lo);
        size_t hidx = ((size_t)v * B_ + bp) * H_ + n;
        hattHi[hidx] = hi;
        hattLo[hidx] = lo;
      }
    }
}

// ---------------- output projection + clip + prev update ----------------
__global__ __launch_bounds__(256) void out_kernel(
    const u16* __restrict__ hHi, const u16* __restrict__ hLo,
    const float* __restrict__ W_out, const float* __restrict__ b_out,
    float* __restrict__ prev, float* __restrict__ out, int p)
{
  int gid = blockIdx.x * 256 + threadIdx.x;   // V*B*F = 32768
  int row = gid >> 3;
  int f = gid & 7;
  int v = row >> 8, b = row & 255;
  const u16* hp = hHi + (size_t)row * H_;
  const u16* lp = hLo + (size_t)row * H_;
  const float* wp = W_out + f * H_;
  float acc = 0.f;
  #pragma unroll 4
  for (int k = 0; k < H_; k += 8) {
    uint4 hv = *(const uint4*)(hp + k);
    uint4 lv = *(const uint4*)(lp + k);
    float4 w0 = *(const float4*)(wp + k);
    float4 w1 = *(const float4*)(wp + k + 4);
    acc = fmaf(bf2f((u16)(hv.x & 0xffff)) + bf2f((u16)(lv.x & 0xffff)), w0.x, acc);
    acc = fmaf(bf2f((u16)(hv.x >> 16))    + bf2f((u16)(lv.x >> 16)),    w0.y, acc);
    acc = fmaf(bf2f((u16)(hv.y & 0xffff)) + bf2f((u16)(lv.y & 0xffff)), w0.z, acc);
    acc = fmaf(bf2f((u16)(hv.y >> 16))    + bf2f((u16)(lv.y >> 16)),    w0.w, acc);
    acc = fmaf(bf2f((u16)(hv.z & 0xffff)) + bf2f((u16)(lv.z & 0xffff)), w1.x, acc);
    acc = fmaf(bf2f((u16)(hv.z >> 16))    + bf2f((u16)(lv.z >> 16)),    w1.y, acc);
    acc = fmaf(bf2f((u16)(hv.w & 0xffff)) + bf2f((u16)(lv.w & 0xffff)), w1.z, acc);
    acc = fmaf(bf2f((u16)(hv.w >> 16))    + bf2f((u16)(lv.w >> 16)),    w1.w, acc);
  }
  float o = fmaxf(acc + b_out[f], 0.f);
  prev[gid] = o;
  if (f < 4)
    out[(((size_t)b * V_ + v) * P_ + p) * 4 + f] = fminf(o, 1.f);
}

}  // namespace

extern "C" void kernel_launch(void* const* d_in, const int* in_sizes, int n_in,
                              void* d_out, int out_size, void* d_ws, size_t ws_size,
                              hipStream_t stream)
{
  const float* seq   = (const float*)d_in[0];
  const float* smask = (const float*)d_in[4];
  const float* maxv  = (const float*)d_in[5];
  const float* minv  = (const float*)d_in[6];
  const float* W_ih  = (const float*)d_in[7];
  const float* W_hh  = (const float*)d_in[8];
  const float* b_ih  = (const float*)d_in[9];
  const float* b_hh  = (const float*)d_in[10];
  const float* W_att = (const float*)d_in[11];
  const float* b_att = (const float*)d_in[12];
  const float* W_out = (const float*)d_in[13];
  const float* b_out = (const float*)d_in[14];
  float* out = (float*)d_out;

  char* ws = (char*)d_ws;
  float* c     = (float*)(ws);                 //  4,194,304
  float* prev  = (float*)(ws + 4194304);       //    131,072
  u16* h_lo    = (u16*)(ws + 4325376);         //  4,194,304 (2 bufs)
  u16* hdecHi  = (u16*)(ws + 8519680);         //  2,097,152
  u16* hdecLo  = (u16*)(ws + 10616832);        //  2,097,152
  u16* hattHi  = (u16*)(ws + 12713984);        //  2,097,152
  u16* hattLo  = (u16*)(ws + 14811136);        //  2,097,152
  u16* cvHi    = (u16*)(ws + 16908288);        //  2,097,152
  u16* cvLo    = (u16*)(ws + 19005440);        //  2,097,152
  u16* whhHi   = (u16*)(ws + 21102592);        //  8,388,608
  u16* whhLo   = (u16*)(ws + 29491200);        //  8,388,608
  u16* wattHi  = (u16*)(ws + 37879808);        //  4,194,304
  u16* wattLo  = (u16*)(ws + 42074112);        //  4,194,304
  u16* enc     = (u16*)(ws + 46268416);        // 134,217,728

  init_kernel<<<1024, 256, 0, stream>>>(c, prev, seq);
  convert_kernel<<<6144, 256, 0, stream>>>(W_hh, W_att, whhHi, whhLo, wattHi, wattLo);

  // persistent cooperative encoder: 64 steps in one launch
  {
    void* args[] = {
      (void*)&seq, (void*)&enc, (void*)&h_lo, (void*)&c,
      (void*)&whhHi, (void*)&whhLo, (void*)&W_ih, (void*)&b_ih, (void*)&b_hh
    };
    hipLaunchCooperativeKernel((const void*)enc_persist_kernel,
                               dim3(256), dim3(512), args, 0, stream);
  }

  copy_h_kernel<<<512, 256, 0, stream>>>(enc, h_lo + (size_t)V_ * B_ * H_, hdecHi, hdecLo);

  for (int p = 0; p < P_; ++p) {
    attn_kernel<<<V_ * B_, 256, 0, stream>>>(enc, hdecHi, hdecLo, smask, cvHi, cvLo);
    attg_mfma_kernel<<<256, 256, 0, stream>>>(cvHi, cvLo, hdecHi, hdecLo,
        wattHi, wattLo, b_att, hattHi, hattLo);
    lstm_mfma_kernel<1><<<256, 512, 0, stream>>>(prev, nullptr, nullptr, nullptr,
        hattHi, hattLo, hdecHi, hdecLo, c, whhHi, whhLo,
        W_ih, b_ih, b_hh, maxv, minv, 1);
    out_kernel<<<128, 256, 0, stream>>>(hdecHi, hdecLo, W_out, b_out, prev, out, p);
  }
}